// Round 1
// baseline (433.904 us; speedup 1.0000x reference)
//
#include <hip/hip_runtime.h>
#include <stdint.h>

#define SEQ 2048
// B=2, DIM=2048, NH=16, NKV=4, HD=128, qkv width = 2048+512+512 = 3072

typedef uint16_t u16;
typedef uint32_t u32;
typedef __attribute__((ext_vector_type(4))) float f32x4;
typedef __attribute__((ext_vector_type(8))) __bf16 bf16x8;

__device__ __forceinline__ u16 f2bf(float f) {
    u32 u = __float_as_uint(f);
    u += 0x7FFFu + ((u >> 16) & 1u);   // RNE
    return (u16)(u >> 16);
}
__device__ __forceinline__ float bf2f(u16 h) {
    return __uint_as_float(((u32)h) << 16);
}
__device__ __forceinline__ void async16(const void* g, void* l) {
    auto gp = (__attribute__((address_space(1))) void*)const_cast<void*>(g);
    auto lp = (__attribute__((address_space(3))) void*)l;
    __builtin_amdgcn_global_load_lds(gp, lp, 16, 0, 0);
}

// ---------------- fp32 -> bf16 elementwise (x) ----------------
__global__ __launch_bounds__(256) void convert_bf16(const float* __restrict__ src,
                                                    u16* __restrict__ dst) {
    int i = blockIdx.x * 256 + threadIdx.x;      // one float4 per thread
    float4 v = ((const float4*)src)[i];
    u32 lo = (u32)f2bf(v.x) | ((u32)f2bf(v.y) << 16);
    u32 hi = (u32)f2bf(v.z) | ((u32)f2bf(v.w) << 16);
    ((uint2*)dst)[i] = make_uint2(lo, hi);
}

// ------------- fp32 [K][N] -> bf16 transposed [N][K] (weights) -------------
// grid (N/64, K/64); dst row stride = 2048 (=K)
__global__ __launch_bounds__(256) void tconv(const float* __restrict__ src,
                                             u16* __restrict__ dst, int N, int K) {
    __shared__ float tile[64][65];
    const int n0 = blockIdx.x * 64, k0 = blockIdx.y * 64;
    const int tid = threadIdx.x;
#pragma unroll
    for (int p = 0; p < 4; p++) {
        int r = p * 16 + (tid >> 4);
        int c = (tid & 15) * 4;
        float4 v = *(const float4*)&src[(size_t)(k0 + r) * N + n0 + c];
        tile[r][c] = v.x; tile[r][c+1] = v.y; tile[r][c+2] = v.z; tile[r][c+3] = v.w;
    }
    __syncthreads();
#pragma unroll
    for (int p = 0; p < 4; p++) {
        int n = p * 16 + (tid >> 4);
        int kq = (tid & 15) * 4;
        u32 lo = (u32)f2bf(tile[kq+0][n]) | ((u32)f2bf(tile[kq+1][n]) << 16);
        u32 hi = (u32)f2bf(tile[kq+2][n]) | ((u32)f2bf(tile[kq+3][n]) << 16);
        *(uint2*)&dst[(size_t)(n0 + n) * K + k0 + kq] = make_uint2(lo, hi);
    }
}

// ---------------- bf16 GEMM: C[M,N] = A[M,K] * B[K,N], B given as Bt[N,K] ----------------
// 128x128 tile, BK=32, 256 threads (4 waves 2x2 of 64x64), global_load_lds staging,
// XOR-swizzled LDS chunks (chunk' = chunk ^ (row&3)) to break frag-read bank conflicts.
template <bool F32OUT>
__global__ __launch_bounds__(256) void gemm128(const u16* __restrict__ A,
                                               const u16* __restrict__ Bt,
                                               void* __restrict__ Cv,
                                               int M, int N, int K) {
    __shared__ u16 lA[128 * 32];
    __shared__ u16 lB[128 * 32];
    const int tid = threadIdx.x;
    const int m0 = blockIdx.y * 128, n0 = blockIdx.x * 128;
    const int lane = tid & 63;
    const int lr = lane & 15, quad = lane >> 4;
    const int w = tid >> 6;
    const int wm = (w >> 1) * 64, wn = (w & 1) * 64;

    f32x4 acc[4][4] = {};

    const int srow = tid >> 2;                       // 0..63
    const int schunk = (tid & 3) ^ (srow & 3);       // swizzle
    const u16* aS0 = A  + (size_t)(m0 + srow) * K + schunk * 8;
    const u16* aS1 = aS0 + (size_t)64 * K;
    const u16* bS0 = Bt + (size_t)(n0 + srow) * K + schunk * 8;
    const u16* bS1 = bS0 + (size_t)64 * K;
    u16* lAd = lA + tid * 8;
    u16* lBd = lB + tid * 8;

    const int aoff[4] = { (wm + 0*16 + lr) * 32 + ((0 ^ (lr & 3)) ? 0 : 0), 0, 0, 0 }; // placeholder removed below
    (void)aoff;

    for (int k0 = 0; k0 < K; k0 += 32) {
        __syncthreads();
        async16(aS0 + k0, lAd);
        async16(aS1 + k0, lAd + 2048);
        async16(bS0 + k0, lBd);
        async16(bS1 + k0, lBd + 2048);
        __syncthreads();
        bf16x8 af[4], bfr[4];
        const int cs = (quad ^ (lr & 3)) * 8;
#pragma unroll
        for (int i = 0; i < 4; i++)
            af[i] = *(const bf16x8*)&lA[(wm + i * 16 + lr) * 32 + cs];
#pragma unroll
        for (int i = 0; i < 4; i++)
            bfr[i] = *(const bf16x8*)&lB[(wn + i * 16 + lr) * 32 + cs];
#pragma unroll
        for (int mf = 0; mf < 4; mf++)
#pragma unroll
            for (int nf = 0; nf < 4; nf++)
                acc[mf][nf] = __builtin_amdgcn_mfma_f32_16x16x32_bf16(
                    af[mf], bfr[nf], acc[mf][nf], 0, 0, 0);
    }

#pragma unroll
    for (int mf = 0; mf < 4; mf++) {
#pragma unroll
        for (int nf = 0; nf < 4; nf++) {
#pragma unroll
            for (int r = 0; r < 4; r++) {
                size_t row = (size_t)(m0 + wm + mf * 16 + quad * 4 + r);
                size_t col = (size_t)(n0 + wn + nf * 16 + lr);
                if (F32OUT)
                    ((float*)Cv)[row * (size_t)N + col] = acc[mf][nf][r];
                else
                    ((u16*)Cv)[row * (size_t)N + col] = f2bf(acc[mf][nf][r]);
            }
        }
    }
}

// ---------------- in-place interleaved RoPE on q (cols 0..2047) and k (2048..2559) ----------------
// grid = 4096 tokens, 256 threads, 5 pairs/thread (1280 pairs/token)
__global__ __launch_bounds__(256) void rope_qk(u16* __restrict__ qkv,
                                               const float* __restrict__ cosp,
                                               const float* __restrict__ sinp) {
    const int t = blockIdx.x;
    const int spos = t & (SEQ - 1);
    const int tid = threadIdx.x;
    u16* row = qkv + (size_t)t * 3072;
#pragma unroll
    for (int it = 0; it < 5; it++) {
        int p = it * 256 + tid;              // 0..1279
        int col, ci;
        if (p < 1024) { col = 2 * p; ci = p & 63; }
        else          { int p2 = p - 1024; col = 2048 + 2 * p2; ci = p2 & 63; }
        u32 v = *(u32*)(row + col);
        float tr = bf2f((u16)(v & 0xFFFFu));
        float ti = bf2f((u16)(v >> 16));
        float cs = cosp[spos * 64 + ci];
        float sn = sinp[spos * 64 + ci];
        float orr = tr * cs - ti * sn;
        float oi  = tr * sn + ti * cs;
        *(u32*)(row + col) = (u32)f2bf(orr) | ((u32)f2bf(oi) << 16);
    }
}

// ---------------- V: qkv[t][2560 + kh*128 + d] -> vt[(b*4+kh)*128 + d][s] ----------------
// grid = 512: bid = (((b*4+kh)<<6) | (st<<1) | dt)
__global__ __launch_bounds__(256) void transpose_v(const u16* __restrict__ qkv,
                                                   u16* __restrict__ vt) {
    __shared__ u16 tile[64][65];
    const int bid = blockIdx.x;
    const int dt = bid & 1;
    const int st = (bid >> 1) & 31;
    const int kh = (bid >> 6) & 3;
    const int b  = bid >> 8;
    const int tid = threadIdx.x;
#pragma unroll
    for (int pp = 0; pp < 2; pp++) {
        int r  = pp * 32 + (tid >> 3);
        int c8 = (tid & 7) * 8;
        const u16* src = qkv + (size_t)(b * SEQ + st * 64 + r) * 3072 + 2560 + kh * 128 + dt * 64 + c8;
        uint4 v = *(const uint4*)src;
        tile[r][c8+0] = (u16)(v.x & 0xFFFF); tile[r][c8+1] = (u16)(v.x >> 16);
        tile[r][c8+2] = (u16)(v.y & 0xFFFF); tile[r][c8+3] = (u16)(v.y >> 16);
        tile[r][c8+4] = (u16)(v.z & 0xFFFF); tile[r][c8+5] = (u16)(v.z >> 16);
        tile[r][c8+6] = (u16)(v.w & 0xFFFF); tile[r][c8+7] = (u16)(v.w >> 16);
    }
    __syncthreads();
#pragma unroll
    for (int pp = 0; pp < 2; pp++) {
        int dr = pp * 32 + (tid >> 3);
        int s8 = (tid & 7) * 8;
        uint4 o;
        o.x = (u32)tile[s8+0][dr] | ((u32)tile[s8+1][dr] << 16);
        o.y = (u32)tile[s8+2][dr] | ((u32)tile[s8+3][dr] << 16);
        o.z = (u32)tile[s8+4][dr] | ((u32)tile[s8+5][dr] << 16);
        o.w = (u32)tile[s8+6][dr] | ((u32)tile[s8+7][dr] << 16);
        u16* dst = vt + ((size_t)((b * 4 + kh) * 128 + dt * 64 + dr)) * SEQ + st * 64 + s8;
        *(uint4*)dst = o;
    }
}

// ---------------- causal GQA flash attention ----------------
// grid = B*NH*(S/64) = 1024.  64 q-rows per block, 4 waves x 16 rows.
// K-tile (64 tok x 128 d) and V^T-tile (128 d x 64 tok) staged with global_load_lds,
// XOR chunk swizzle; P goes C-layout -> LDS -> A-layout (per-wave region).
__global__ __launch_bounds__(256) void flash_attn(const u16* __restrict__ qkv,
                                                  const u16* __restrict__ vt,
                                                  u16* __restrict__ ob) {
    __shared__ u16 lK[64 * 128];
    __shared__ u16 lV[128 * 64];
    __shared__ u16 lP[4 * 16 * 64];
    const int bidx = blockIdx.x;
    const int qt = 31 - (bidx & 31);      // heavy tiles first
    const int h  = (bidx >> 5) & 15;
    const int b  = bidx >> 9;
    const int kh = h >> 2;
    const int tid = threadIdx.x;
    const int w = tid >> 6, lane = tid & 63;
    const int lr = lane & 15, quad = lane >> 4;
    const float c1 = 0.088388347762f * 1.4426950408889634f;   // (1/sqrt(128))*log2(e)

    // Q fragments (A-layout), held in registers for the whole block
    bf16x8 qf[4];
    {
        const u16* qbase = qkv + (size_t)(b * SEQ + qt * 64 + w * 16 + lr) * 3072 + h * 128;
#pragma unroll
        for (int kk = 0; kk < 4; kk++)
            qf[kk] = *(const bf16x8*)(qbase + kk * 32 + quad * 8);
    }

    f32x4 o[8] = {};
    float mrow[4] = {-1e30f, -1e30f, -1e30f, -1e30f};
    float lrow[4] = {0.f, 0.f, 0.f, 0.f};

    // staging address precompute
    const int krow = tid >> 4;                 // 0..15
    const int kchunk = (tid & 15) ^ krow;      // 16 chunks/row swizzle
    const int vrow = tid >> 3;                 // 0..31
    const int vchunk = (tid & 7) ^ (vrow & 7); // 8 chunks/row swizzle
    const u16* kRow = qkv + (size_t)b * SEQ * 3072 + 2048 + kh * 128
                    + (size_t)krow * 3072 + kchunk * 8;
    const u16* vRow = vt + (size_t)(b * 4 + kh) * 128 * SEQ
                    + (size_t)vrow * SEQ + vchunk * 8;
    u16* lKd = lK + tid * 8;
    u16* lVd = lV + tid * 8;

    for (int kt = 0; kt <= qt; kt++) {
        __syncthreads();
#pragma unroll
        for (int i = 0; i < 4; i++)
            async16(kRow + (size_t)(kt * 64 + i * 16) * 3072, lKd + i * 2048);
#pragma unroll
        for (int i = 0; i < 4; i++)
            async16(vRow + (size_t)(i * 32) * SEQ + kt * 64, lVd + i * 2048);
        __syncthreads();

        // S = Q K^T   (per-wave 16 rows x 64 keys)
        f32x4 sc[4] = {};
#pragma unroll
        for (int nf = 0; nf < 4; nf++) {
#pragma unroll
            for (int kk = 0; kk < 4; kk++) {
                bf16x8 bk = *(const bf16x8*)&lK[(nf * 16 + lr) * 128 + (((kk * 4 + quad) ^ lr) * 8)];
                sc[nf] = __builtin_amdgcn_mfma_f32_16x16x32_bf16(qf[kk], bk, sc[nf], 0, 0, 0);
            }
        }

        // online softmax (exp2 domain)
        float sv[4][4];
        float mnew[4] = {mrow[0], mrow[1], mrow[2], mrow[3]};
        const bool diag = (kt == qt);
#pragma unroll
        for (int nf = 0; nf < 4; nf++)
#pragma unroll
            for (int r = 0; r < 4; r++) {
                float v = sc[nf][r] * c1;
                if (diag && (nf * 16 + lr) > (w * 16 + quad * 4 + r)) v = -1e30f;
                sv[nf][r] = v;
                mnew[r] = fmaxf(mnew[r], v);
            }
#pragma unroll
        for (int r = 0; r < 4; r++) {
            mnew[r] = fmaxf(mnew[r], __shfl_xor(mnew[r], 1, 16));
            mnew[r] = fmaxf(mnew[r], __shfl_xor(mnew[r], 2, 16));
            mnew[r] = fmaxf(mnew[r], __shfl_xor(mnew[r], 4, 16));
            mnew[r] = fmaxf(mnew[r], __shfl_xor(mnew[r], 8, 16));
        }
        float rsum[4] = {0.f, 0.f, 0.f, 0.f};
#pragma unroll
        for (int nf = 0; nf < 4; nf++)
#pragma unroll
            for (int r = 0; r < 4; r++) {
                float e = exp2f(sv[nf][r] - mnew[r]);
                sv[nf][r] = e;
                rsum[r] += e;
            }
#pragma unroll
        for (int r = 0; r < 4; r++) {
            rsum[r] += __shfl_xor(rsum[r], 1, 16);
            rsum[r] += __shfl_xor(rsum[r], 2, 16);
            rsum[r] += __shfl_xor(rsum[r], 4, 16);
            rsum[r] += __shfl_xor(rsum[r], 8, 16);
        }
#pragma unroll
        for (int r = 0; r < 4; r++) {
            float alpha = exp2f(mrow[r] - mnew[r]);
            lrow[r] = lrow[r] * alpha + rsum[r];
            mrow[r] = mnew[r];
#pragma unroll
            for (int f = 0; f < 8; f++) o[f][r] *= alpha;
        }

        // P: C-layout -> LDS (per-wave region, swizzled 8-chunk rows)
#pragma unroll
        for (int nf = 0; nf < 4; nf++)
#pragma unroll
            for (int r = 0; r < 4; r++) {
                int m_ = quad * 4 + r;
                int khi = nf * 2 + (lr >> 3);
                lP[w * 1024 + m_ * 64 + ((khi ^ (m_ & 7)) * 8) + (lr & 7)] = f2bf(sv[nf][r]);
            }
        __syncthreads();

        // O += P V
#pragma unroll
        for (int kf = 0; kf < 2; kf++) {
            bf16x8 pa = *(const bf16x8*)&lP[w * 1024 + lr * 64 + (((kf * 4 + quad) ^ (lr & 7)) * 8)];
#pragma unroll
            for (int nf = 0; nf < 8; nf++) {
                bf16x8 vb = *(const bf16x8*)&lV[(nf * 16 + lr) * 64 + (((kf * 4 + quad) ^ (lr & 7)) * 8)];
                o[nf] = __builtin_amdgcn_mfma_f32_16x16x32_bf16(pa, vb, o[nf], 0, 0, 0);
            }
        }
    }

    u16* obase = ob + (size_t)(b * SEQ + qt * 64 + w * 16) * 2048 + h * 128;
#pragma unroll
    for (int r = 0; r < 4; r++) {
        float rinv = 1.0f / lrow[r];
#pragma unroll
        for (int f = 0; f < 8; f++)
            obase[(quad * 4 + r) * 2048 + f * 16 + lr] = f2bf(o[f][r] * rinv);
    }
}

extern "C" void kernel_launch(void* const* d_in, const int* in_sizes, int n_in,
                              void* d_out, int out_size, void* d_ws, size_t ws_size,
                              hipStream_t stream) {
    (void)in_sizes; (void)n_in; (void)out_size; (void)ws_size;
    const float* x    = (const float*)d_in[0];
    const float* cosp = (const float*)d_in[1];
    const float* sinp = (const float*)d_in[2];
    const float* wq   = (const float*)d_in[3];
    const float* wk   = (const float*)d_in[4];
    const float* wv   = (const float*)d_in[5];
    const float* wo   = (const float*)d_in[6];
    float* out = (float*)d_out;

    char* ws = (char*)d_ws;
    u16* xb    = (u16*)(ws);                               // 16 MB (reused as ob)
    u16* qkvb  = (u16*)(ws + (size_t)16 * 1024 * 1024);    // 24 MB
    u16* wqkvT = (u16*)(ws + (size_t)40 * 1024 * 1024);    // 12 MB
    u16* woT   = (u16*)(ws + (size_t)52 * 1024 * 1024);    //  8 MB
    u16* vtb   = (u16*)(ws + (size_t)60 * 1024 * 1024);    //  4 MB
    u16* ob    = xb;                                       // alias: xb dead after QKV GEMM

    convert_bf16<<<8192, 256, 0, stream>>>(x, xb);
    tconv<<<dim3(32, 32), 256, 0, stream>>>(wq, wqkvT, 2048, 2048);
    tconv<<<dim3( 8, 32), 256, 0, stream>>>(wk, wqkvT + (size_t)2048 * 2048, 512, 2048);
    tconv<<<dim3( 8, 32), 256, 0, stream>>>(wv, wqkvT + (size_t)2560 * 2048, 512, 2048);
    tconv<<<dim3(32, 32), 256, 0, stream>>>(wo, woT, 2048, 2048);
    gemm128<false><<<dim3(24, 32), 256, 0, stream>>>(xb, wqkvT, (void*)qkvb, 4096, 3072, 2048);
    rope_qk<<<4096, 256, 0, stream>>>(qkvb, cosp, sinp);
    transpose_v<<<512, 256, 0, stream>>>(qkvb, vtb);
    flash_attn<<<1024, 256, 0, stream>>>(qkvb, vtb, ob);
    gemm128<true><<<dim3(16, 32), 256, 0, stream>>>(ob, woT, (void*)out, 4096, 2048, 2048);
}

// Round 2
// 362.961 us; speedup vs baseline: 1.1955x; 1.1955x over previous
//
#include <hip/hip_runtime.h>
#include <stdint.h>

#define SEQ 2048
// B=2, DIM=2048, NH=16, NKV=4, HD=128, qkv width = 2048+512+512 = 3072

typedef uint16_t u16;
typedef uint32_t u32;
typedef __attribute__((ext_vector_type(4))) float f32x4;
typedef __attribute__((ext_vector_type(8))) __bf16 bf16x8;

__device__ __forceinline__ u16 f2bf(float f) {
    u32 u = __float_as_uint(f);
    u += 0x7FFFu + ((u >> 16) & 1u);   // RNE
    return (u16)(u >> 16);
}
__device__ __forceinline__ float bf2f(u16 h) {
    return __uint_as_float(((u32)h) << 16);
}
__device__ __forceinline__ void async16(const void* g, void* l) {
    auto gp = (__attribute__((address_space(1))) void*)const_cast<void*>(g);
    auto lp = (__attribute__((address_space(3))) void*)l;
    __builtin_amdgcn_global_load_lds(gp, lp, 16, 0, 0);
}

// ---------------- fp32 -> bf16 elementwise (x) ----------------
__global__ __launch_bounds__(256) void convert_bf16(const float* __restrict__ src,
                                                    u16* __restrict__ dst) {
    int i = blockIdx.x * 256 + threadIdx.x;      // one float4 per thread
    float4 v = ((const float4*)src)[i];
    u32 lo = (u32)f2bf(v.x) | ((u32)f2bf(v.y) << 16);
    u32 hi = (u32)f2bf(v.z) | ((u32)f2bf(v.w) << 16);
    ((uint2*)dst)[i] = make_uint2(lo, hi);
}

// ------------- fp32 [K][N] -> bf16 transposed [N][K] (weights) -------------
__global__ __launch_bounds__(256) void tconv(const float* __restrict__ src,
                                             u16* __restrict__ dst, int N, int K) {
    __shared__ float tile[64][65];
    const int n0 = blockIdx.x * 64, k0 = blockIdx.y * 64;
    const int tid = threadIdx.x;
#pragma unroll
    for (int p = 0; p < 4; p++) {
        int r = p * 16 + (tid >> 4);
        int c = (tid & 15) * 4;
        float4 v = *(const float4*)&src[(size_t)(k0 + r) * N + n0 + c];
        tile[r][c] = v.x; tile[r][c+1] = v.y; tile[r][c+2] = v.z; tile[r][c+3] = v.w;
    }
    __syncthreads();
#pragma unroll
    for (int p = 0; p < 4; p++) {
        int n = p * 16 + (tid >> 4);
        int kq = (tid & 15) * 4;
        u32 lo = (u32)f2bf(tile[kq+0][n]) | ((u32)f2bf(tile[kq+1][n]) << 16);
        u32 hi = (u32)f2bf(tile[kq+2][n]) | ((u32)f2bf(tile[kq+3][n]) << 16);
        *(uint2*)&dst[(size_t)(n0 + n) * K + k0 + kq] = make_uint2(lo, hi);
    }
}

// ---------------- bf16 GEMM: C[M,N] = A[M,K] * Bt[N,K]^T ----------------
template <bool F32OUT>
__global__ __launch_bounds__(256) void gemm128(const u16* __restrict__ A,
                                               const u16* __restrict__ Bt,
                                               void* __restrict__ Cv,
                                               int M, int N, int K) {
    __shared__ u16 lA[128 * 32];
    __shared__ u16 lB[128 * 32];
    const int tid = threadIdx.x;
    const int m0 = blockIdx.y * 128, n0 = blockIdx.x * 128;
    const int lane = tid & 63;
    const int lr = lane & 15, quad = lane >> 4;
    const int w = tid >> 6;
    const int wm = (w >> 1) * 64, wn = (w & 1) * 64;

    f32x4 acc[4][4] = {};

    const int srow = tid >> 2;
    const int schunk = (tid & 3) ^ (srow & 3);
    const u16* aS0 = A  + (size_t)(m0 + srow) * K + schunk * 8;
    const u16* aS1 = aS0 + (size_t)64 * K;
    const u16* bS0 = Bt + (size_t)(n0 + srow) * K + schunk * 8;
    const u16* bS1 = bS0 + (size_t)64 * K;
    u16* lAd = lA + tid * 8;
    u16* lBd = lB + tid * 8;

    for (int k0 = 0; k0 < K; k0 += 32) {
        __syncthreads();
        async16(aS0 + k0, lAd);
        async16(aS1 + k0, lAd + 2048);
        async16(bS0 + k0, lBd);
        async16(bS1 + k0, lBd + 2048);
        __syncthreads();
        bf16x8 af[4], bfr[4];
        const int cs = (quad ^ (lr & 3)) * 8;
#pragma unroll
        for (int i = 0; i < 4; i++)
            af[i] = *(const bf16x8*)&lA[(wm + i * 16 + lr) * 32 + cs];
#pragma unroll
        for (int i = 0; i < 4; i++)
            bfr[i] = *(const bf16x8*)&lB[(wn + i * 16 + lr) * 32 + cs];
#pragma unroll
        for (int mf = 0; mf < 4; mf++)
#pragma unroll
            for (int nf = 0; nf < 4; nf++)
                acc[mf][nf] = __builtin_amdgcn_mfma_f32_16x16x32_bf16(
                    af[mf], bfr[nf], acc[mf][nf], 0, 0, 0);
    }

#pragma unroll
    for (int mf = 0; mf < 4; mf++) {
#pragma unroll
        for (int nf = 0; nf < 4; nf++) {
#pragma unroll
            for (int r = 0; r < 4; r++) {
                size_t row = (size_t)(m0 + wm + mf * 16 + quad * 4 + r);
                size_t col = (size_t)(n0 + wn + nf * 16 + lr);
                if (F32OUT)
                    ((float*)Cv)[row * (size_t)N + col] = acc[mf][nf][r];
                else
                    ((u16*)Cv)[row * (size_t)N + col] = f2bf(acc[mf][nf][r]);
            }
        }
    }
}

// ---------------- RoPE; Q additionally scaled by (1/sqrt(HD))*log2(e) ----------------
__global__ __launch_bounds__(256) void rope_qk(u16* __restrict__ qkv,
                                               const float* __restrict__ cosp,
                                               const float* __restrict__ sinp) {
    const int t = blockIdx.x;
    const int spos = t & (SEQ - 1);
    const int tid = threadIdx.x;
    const float qscale = 0.088388347762f * 1.4426950408889634f;
    u16* row = qkv + (size_t)t * 3072;
#pragma unroll
    for (int it = 0; it < 5; it++) {
        int p = it * 256 + tid;              // 0..1279
        int col, ci; float sc2;
        if (p < 1024) { col = 2 * p; ci = p & 63; sc2 = qscale; }
        else          { int p2 = p - 1024; col = 2048 + 2 * p2; ci = p2 & 63; sc2 = 1.0f; }
        u32 v = *(u32*)(row + col);
        float tr = bf2f((u16)(v & 0xFFFFu));
        float ti = bf2f((u16)(v >> 16));
        float cs = cosp[spos * 64 + ci];
        float sn = sinp[spos * 64 + ci];
        float orr = (tr * cs - ti * sn) * sc2;
        float oi  = (tr * sn + ti * cs) * sc2;
        *(u32*)(row + col) = (u32)f2bf(orr) | ((u32)f2bf(oi) << 16);
    }
}

// ---------------- V: qkv[t][2560 + kh*128 + d] -> vt[(b*4+kh)*128 + d][s] ----------------
__global__ __launch_bounds__(256) void transpose_v(const u16* __restrict__ qkv,
                                                   u16* __restrict__ vt) {
    __shared__ u16 tile[64][65];
    const int bid = blockIdx.x;
    const int dt = bid & 1;
    const int st = (bid >> 1) & 31;
    const int kh = (bid >> 6) & 3;
    const int b  = bid >> 8;
    const int tid = threadIdx.x;
#pragma unroll
    for (int pp = 0; pp < 2; pp++) {
        int r  = pp * 32 + (tid >> 3);
        int c8 = (tid & 7) * 8;
        const u16* src = qkv + (size_t)(b * SEQ + st * 64 + r) * 3072 + 2560 + kh * 128 + dt * 64 + c8;
        uint4 v = *(const uint4*)src;
        tile[r][c8+0] = (u16)(v.x & 0xFFFF); tile[r][c8+1] = (u16)(v.x >> 16);
        tile[r][c8+2] = (u16)(v.y & 0xFFFF); tile[r][c8+3] = (u16)(v.y >> 16);
        tile[r][c8+4] = (u16)(v.z & 0xFFFF); tile[r][c8+5] = (u16)(v.z >> 16);
        tile[r][c8+6] = (u16)(v.w & 0xFFFF); tile[r][c8+7] = (u16)(v.w >> 16);
    }
    __syncthreads();
#pragma unroll
    for (int pp = 0; pp < 2; pp++) {
        int dr = pp * 32 + (tid >> 3);
        int s8 = (tid & 7) * 8;
        uint4 o;
        o.x = (u32)tile[s8+0][dr] | ((u32)tile[s8+1][dr] << 16);
        o.y = (u32)tile[s8+2][dr] | ((u32)tile[s8+3][dr] << 16);
        o.z = (u32)tile[s8+4][dr] | ((u32)tile[s8+5][dr] << 16);
        o.w = (u32)tile[s8+6][dr] | ((u32)tile[s8+7][dr] << 16);
        u16* dst = vt + ((size_t)((b * 4 + kh) * 128 + dt * 64 + dr)) * SEQ + st * 64 + s8;
        *(uint4*)dst = o;
    }
}

// ---------------- causal GQA flash attention, balanced pairs + double buffer ----------------
// grid = B*NH*16 = 512 blocks; block bidx handles q-tiles {31-qa, qa} -> exactly 33 K-tiles each.
// K/V double-buffered via global_load_lds + raw s_barrier + manual vmcnt (no full drains).
__global__ __launch_bounds__(256) void flash_attn(const u16* __restrict__ qkv,
                                                  const u16* __restrict__ vt,
                                                  u16* __restrict__ ob) {
    __shared__ u16 lK[2][64 * 128];
    __shared__ u16 lV[2][128 * 64];
    __shared__ u16 lP[4 * 16 * 64];
    const int bidx = blockIdx.x;
    const int qa = bidx & 15;
    const int h  = (bidx >> 4) & 15;
    const int b  = bidx >> 8;
    const int kh = h >> 2;
    const int tid = threadIdx.x;
    const int w = tid >> 6, lane = tid & 63;
    const int lr = lane & 15, quad = lane >> 4;

    // staging address precompute (scale*log2e already folded into Q by rope_qk)
    const int krow = tid >> 4;                 // 0..15
    const int kchunk = (tid & 15) ^ krow;      // swizzle
    const int vrow = tid >> 3;                 // 0..31
    const int vchunk = (tid & 7) ^ (vrow & 7);
    const u16* kRow = qkv + (size_t)b * SEQ * 3072 + 2048 + kh * 128
                    + (size_t)krow * 3072 + kchunk * 8;
    const u16* vRow = vt + (size_t)(b * 4 + kh) * 128 * SEQ
                    + (size_t)vrow * SEQ + vchunk * 8;

    for (int half = 0; half < 2; half++) {
        const int qt = half ? qa : (31 - qa);   // heavy tile first

        // Q fragments (A-layout) for this q-tile
        bf16x8 qf[4];
        {
            const u16* qbase = qkv + (size_t)(b * SEQ + qt * 64 + w * 16 + lr) * 3072 + h * 128;
#pragma unroll
            for (int kk = 0; kk < 4; kk++)
                qf[kk] = *(const bf16x8*)(qbase + kk * 32 + quad * 8);
        }

        f32x4 o[8] = {};
        float mrow[4] = {-1e30f, -1e30f, -1e30f, -1e30f};
        float lrow[4] = {0.f, 0.f, 0.f, 0.f};

        // prologue: stage tile 0 into buffer 0
        {
            u16* lKd = &lK[0][0] + tid * 8;
            u16* lVd = &lV[0][0] + tid * 8;
#pragma unroll
            for (int i = 0; i < 4; i++)
                async16(kRow + (size_t)(i * 16) * 3072, lKd + i * 2048);
#pragma unroll
            for (int i = 0; i < 4; i++)
                async16(vRow + (size_t)(i * 32) * SEQ, lVd + i * 2048);
        }

        int nb = 0;
        for (int kt = 0; kt <= qt; kt++) {
            if (kt < qt) {   // prefetch next tile into other buffer
                u16* lKd = &lK[nb ^ 1][0] + tid * 8;
                u16* lVd = &lV[nb ^ 1][0] + tid * 8;
#pragma unroll
                for (int i = 0; i < 4; i++)
                    async16(kRow + (size_t)((kt + 1) * 64 + i * 16) * 3072, lKd + i * 2048);
#pragma unroll
                for (int i = 0; i < 4; i++)
                    async16(vRow + (size_t)(i * 32) * SEQ + (kt + 1) * 64, lVd + i * 2048);
                asm volatile("s_waitcnt vmcnt(8)" ::: "memory");
            } else {
                asm volatile("s_waitcnt vmcnt(0)" ::: "memory");
            }
            asm volatile("s_barrier" ::: "memory");   // all waves' cur-buffer loads complete

            const u16* lKc = &lK[nb][0];
            const u16* lVc = &lV[nb][0];

            // S = Q K^T   (per-wave 16 rows x 64 keys); Q pre-scaled -> log2 domain
            f32x4 sc[4] = {};
#pragma unroll
            for (int nf = 0; nf < 4; nf++) {
#pragma unroll
                for (int kk = 0; kk < 4; kk++) {
                    bf16x8 bk = *(const bf16x8*)&lKc[(nf * 16 + lr) * 128 + (((kk * 4 + quad) ^ lr) * 8)];
                    sc[nf] = __builtin_amdgcn_mfma_f32_16x16x32_bf16(qf[kk], bk, sc[nf], 0, 0, 0);
                }
            }

            // online softmax (exp2 domain)
            float sv[4][4];
            float mnew[4] = {mrow[0], mrow[1], mrow[2], mrow[3]};
            const bool diag = (kt == qt);
#pragma unroll
            for (int nf = 0; nf < 4; nf++)
#pragma unroll
                for (int r = 0; r < 4; r++) {
                    float v = sc[nf][r];
                    if (diag && (nf * 16 + lr) > (w * 16 + quad * 4 + r)) v = -1e30f;
                    sv[nf][r] = v;
                    mnew[r] = fmaxf(mnew[r], v);
                }
#pragma unroll
            for (int r = 0; r < 4; r++) {
                mnew[r] = fmaxf(mnew[r], __shfl_xor(mnew[r], 1, 16));
                mnew[r] = fmaxf(mnew[r], __shfl_xor(mnew[r], 2, 16));
                mnew[r] = fmaxf(mnew[r], __shfl_xor(mnew[r], 4, 16));
                mnew[r] = fmaxf(mnew[r], __shfl_xor(mnew[r], 8, 16));
            }
            float rsum[4] = {0.f, 0.f, 0.f, 0.f};
#pragma unroll
            for (int nf = 0; nf < 4; nf++)
#pragma unroll
                for (int r = 0; r < 4; r++) {
                    float e = exp2f(sv[nf][r] - mnew[r]);
                    sv[nf][r] = e;
                    rsum[r] += e;
                }
#pragma unroll
            for (int r = 0; r < 4; r++) {
                rsum[r] += __shfl_xor(rsum[r], 1, 16);
                rsum[r] += __shfl_xor(rsum[r], 2, 16);
                rsum[r] += __shfl_xor(rsum[r], 4, 16);
                rsum[r] += __shfl_xor(rsum[r], 8, 16);
            }
#pragma unroll
            for (int r = 0; r < 4; r++) {
                float alpha = exp2f(mrow[r] - mnew[r]);
                lrow[r] = lrow[r] * alpha + rsum[r];
                mrow[r] = mnew[r];
#pragma unroll
                for (int f = 0; f < 8; f++) o[f][r] *= alpha;
            }

            // P: C-layout -> LDS A-layout (PER-WAVE region; no cross-wave barrier needed)
#pragma unroll
            for (int nf = 0; nf < 4; nf++)
#pragma unroll
                for (int r = 0; r < 4; r++) {
                    int m_ = quad * 4 + r;
                    int khi = nf * 2 + (lr >> 3);
                    lP[w * 1024 + m_ * 64 + ((khi ^ (m_ & 7)) * 8) + (lr & 7)] = f2bf(sv[nf][r]);
                }

            // O += P V
#pragma unroll
            for (int kf = 0; kf < 2; kf++) {
                bf16x8 pa = *(const bf16x8*)&lP[w * 1024 + lr * 64 + (((kf * 4 + quad) ^ (lr & 7)) * 8)];
#pragma unroll
                for (int nf = 0; nf < 8; nf++) {
                    bf16x8 vb = *(const bf16x8*)&lVc[(nf * 16 + lr) * 64 + (((kf * 4 + quad) ^ (lr & 7)) * 8)];
                    o[nf] = __builtin_amdgcn_mfma_f32_16x16x32_bf16(pa, vb, o[nf], 0, 0, 0);
                }
            }

            asm volatile("s_barrier" ::: "memory");   // cur-buffer reads done -> next prefetch may overwrite
            nb ^= 1;
        }

        u16* obase = ob + (size_t)(b * SEQ + qt * 64 + w * 16) * 2048 + h * 128;
#pragma unroll
        for (int r = 0; r < 4; r++) {
            float rinv = 1.0f / lrow[r];
#pragma unroll
            for (int f = 0; f < 8; f++)
                obase[(quad * 4 + r) * 2048 + f * 16 + lr] = f2bf(o[f][r] * rinv);
        }
    }
}

extern "C" void kernel_launch(void* const* d_in, const int* in_sizes, int n_in,
                              void* d_out, int out_size, void* d_ws, size_t ws_size,
                              hipStream_t stream) {
    (void)in_sizes; (void)n_in; (void)out_size; (void)ws_size;
    const float* x    = (const float*)d_in[0];
    const float* cosp = (const float*)d_in[1];
    const float* sinp = (const float*)d_in[2];
    const float* wq   = (const float*)d_in[3];
    const float* wk   = (const float*)d_in[4];
    const float* wv   = (const float*)d_in[5];
    const float* wo   = (const float*)d_in[6];
    float* out = (float*)d_out;

    char* ws = (char*)d_ws;
    u16* xb    = (u16*)(ws);                               // 16 MB (reused as ob)
    u16* qkvb  = (u16*)(ws + (size_t)16 * 1024 * 1024);    // 24 MB
    u16* wqkvT = (u16*)(ws + (size_t)40 * 1024 * 1024);    // 12 MB
    u16* woT   = (u16*)(ws + (size_t)52 * 1024 * 1024);    //  8 MB
    u16* vtb   = (u16*)(ws + (size_t)60 * 1024 * 1024);    //  4 MB
    u16* ob    = xb;                                       // alias: xb dead after QKV GEMM

    convert_bf16<<<8192, 256, 0, stream>>>(x, xb);
    tconv<<<dim3(32, 32), 256, 0, stream>>>(wq, wqkvT, 2048, 2048);
    tconv<<<dim3( 8, 32), 256, 0, stream>>>(wk, wqkvT + (size_t)2048 * 2048, 512, 2048);
    tconv<<<dim3( 8, 32), 256, 0, stream>>>(wv, wqkvT + (size_t)2560 * 2048, 512, 2048);
    tconv<<<dim3(32, 32), 256, 0, stream>>>(wo, woT, 2048, 2048);
    gemm128<false><<<dim3(24, 32), 256, 0, stream>>>(xb, wqkvT, (void*)qkvb, 4096, 3072, 2048);
    rope_qk<<<4096, 256, 0, stream>>>(qkvb, cosp, sinp);
    transpose_v<<<512, 256, 0, stream>>>(qkvb, vtb);
    flash_attn<<<512, 256, 0, stream>>>(qkvb, vtb, ob);
    gemm128<true><<<dim3(16, 32), 256, 0, stream>>>(ob, woT, (void*)out, 4096, 2048, 2048);
}

// Round 3
// 351.619 us; speedup vs baseline: 1.2340x; 1.0323x over previous
//
#include <hip/hip_runtime.h>
#include <stdint.h>

#define SEQ 2048
// B=2, DIM=2048, NH=16, NKV=4, HD=128, qkv width = 2048+512+512 = 3072

typedef uint16_t u16;
typedef uint32_t u32;
typedef __attribute__((ext_vector_type(4))) float f32x4;
typedef __attribute__((ext_vector_type(8))) __bf16 bf16x8;
typedef __attribute__((ext_vector_type(4))) __bf16 bf16x4;

__device__ __forceinline__ u16 f2bf(float f) {
    u32 u = __float_as_uint(f);
    u += 0x7FFFu + ((u >> 16) & 1u);   // RNE
    return (u16)(u >> 16);
}
__device__ __forceinline__ float bf2f(u16 h) {
    return __uint_as_float(((u32)h) << 16);
}
__device__ __forceinline__ void async16(const void* g, void* l) {
    auto gp = (__attribute__((address_space(1))) void*)const_cast<void*>(g);
    auto lp = (__attribute__((address_space(3))) void*)l;
    __builtin_amdgcn_global_load_lds(gp, lp, 16, 0, 0);
}

// ---------------- fp32 -> bf16 elementwise (x) ----------------
__global__ __launch_bounds__(256) void convert_bf16(const float* __restrict__ src,
                                                    u16* __restrict__ dst) {
    int i = blockIdx.x * 256 + threadIdx.x;      // one float4 per thread
    float4 v = ((const float4*)src)[i];
    u32 lo = (u32)f2bf(v.x) | ((u32)f2bf(v.y) << 16);
    u32 hi = (u32)f2bf(v.z) | ((u32)f2bf(v.w) << 16);
    ((uint2*)dst)[i] = make_uint2(lo, hi);
}

// ------------- fp32 [K][N] -> bf16 transposed [N][K] (weights) -------------
__global__ __launch_bounds__(256) void tconv(const float* __restrict__ src,
                                             u16* __restrict__ dst, int N, int K) {
    __shared__ float tile[64][65];
    const int n0 = blockIdx.x * 64, k0 = blockIdx.y * 64;
    const int tid = threadIdx.x;
#pragma unroll
    for (int p = 0; p < 4; p++) {
        int r = p * 16 + (tid >> 4);
        int c = (tid & 15) * 4;
        float4 v = *(const float4*)&src[(size_t)(k0 + r) * N + n0 + c];
        tile[r][c] = v.x; tile[r][c+1] = v.y; tile[r][c+2] = v.z; tile[r][c+3] = v.w;
    }
    __syncthreads();
#pragma unroll
    for (int p = 0; p < 4; p++) {
        int n = p * 16 + (tid >> 4);
        int kq = (tid & 15) * 4;
        u32 lo = (u32)f2bf(tile[kq+0][n]) | ((u32)f2bf(tile[kq+1][n]) << 16);
        u32 hi = (u32)f2bf(tile[kq+2][n]) | ((u32)f2bf(tile[kq+3][n]) << 16);
        *(uint2*)&dst[(size_t)(n0 + n) * K + k0 + kq] = make_uint2(lo, hi);
    }
}

// ---------------- bf16 GEMM: C[M,N] = A[M,K] * Bt[N,K]^T ----------------
template <bool F32OUT>
__global__ __launch_bounds__(256) void gemm128(const u16* __restrict__ A,
                                               const u16* __restrict__ Bt,
                                               void* __restrict__ Cv,
                                               int M, int N, int K) {
    __shared__ u16 lA[128 * 32];
    __shared__ u16 lB[128 * 32];
    const int tid = threadIdx.x;
    const int m0 = blockIdx.y * 128, n0 = blockIdx.x * 128;
    const int lane = tid & 63;
    const int lr = lane & 15, quad = lane >> 4;
    const int w = tid >> 6;
    const int wm = (w >> 1) * 64, wn = (w & 1) * 64;

    f32x4 acc[4][4] = {};

    const int srow = tid >> 2;
    const int schunk = (tid & 3) ^ (srow & 3);
    const u16* aS0 = A  + (size_t)(m0 + srow) * K + schunk * 8;
    const u16* aS1 = aS0 + (size_t)64 * K;
    const u16* bS0 = Bt + (size_t)(n0 + srow) * K + schunk * 8;
    const u16* bS1 = bS0 + (size_t)64 * K;
    u16* lAd = lA + tid * 8;
    u16* lBd = lB + tid * 8;

    for (int k0 = 0; k0 < K; k0 += 32) {
        __syncthreads();
        async16(aS0 + k0, lAd);
        async16(aS1 + k0, lAd + 2048);
        async16(bS0 + k0, lBd);
        async16(bS1 + k0, lBd + 2048);
        __syncthreads();
        bf16x8 af[4], bfr[4];
        const int cs = (quad ^ (lr & 3)) * 8;
#pragma unroll
        for (int i = 0; i < 4; i++)
            af[i] = *(const bf16x8*)&lA[(wm + i * 16 + lr) * 32 + cs];
#pragma unroll
        for (int i = 0; i < 4; i++)
            bfr[i] = *(const bf16x8*)&lB[(wn + i * 16 + lr) * 32 + cs];
#pragma unroll
        for (int mf = 0; mf < 4; mf++)
#pragma unroll
            for (int nf = 0; nf < 4; nf++)
                acc[mf][nf] = __builtin_amdgcn_mfma_f32_16x16x32_bf16(
                    af[mf], bfr[nf], acc[mf][nf], 0, 0, 0);
    }

#pragma unroll
    for (int mf = 0; mf < 4; mf++) {
#pragma unroll
        for (int nf = 0; nf < 4; nf++) {
#pragma unroll
            for (int r = 0; r < 4; r++) {
                size_t row = (size_t)(m0 + wm + mf * 16 + quad * 4 + r);
                size_t col = (size_t)(n0 + wn + nf * 16 + lr);
                if (F32OUT)
                    ((float*)Cv)[row * (size_t)N + col] = acc[mf][nf][r];
                else
                    ((u16*)Cv)[row * (size_t)N + col] = f2bf(acc[mf][nf][r]);
            }
        }
    }
}

// ---------------- RoPE; Q additionally scaled by (1/sqrt(HD))*log2(e) ----------------
__global__ __launch_bounds__(256) void rope_qk(u16* __restrict__ qkv,
                                               const float* __restrict__ cosp,
                                               const float* __restrict__ sinp) {
    const int t = blockIdx.x;
    const int spos = t & (SEQ - 1);
    const int tid = threadIdx.x;
    const float qscale = 0.088388347762f * 1.4426950408889634f;
    u16* row = qkv + (size_t)t * 3072;
#pragma unroll
    for (int it = 0; it < 5; it++) {
        int p = it * 256 + tid;              // 0..1279
        int col, ci; float sc2;
        if (p < 1024) { col = 2 * p; ci = p & 63; sc2 = qscale; }
        else          { int p2 = p - 1024; col = 2048 + 2 * p2; ci = p2 & 63; sc2 = 1.0f; }
        u32 v = *(u32*)(row + col);
        float tr = bf2f((u16)(v & 0xFFFFu));
        float ti = bf2f((u16)(v >> 16));
        float cs = cosp[spos * 64 + ci];
        float sn = sinp[spos * 64 + ci];
        float orr = (tr * cs - ti * sn) * sc2;
        float oi  = (tr * sn + ti * cs) * sc2;
        *(u32*)(row + col) = (u32)f2bf(orr) | ((u32)f2bf(oi) << 16);
    }
}

// ---------------- V: qkv[t][2560 + kh*128 + d] -> vt[(b*4+kh)*128 + d][s] ----------------
__global__ __launch_bounds__(256) void transpose_v(const u16* __restrict__ qkv,
                                                   u16* __restrict__ vt) {
    __shared__ u16 tile[64][65];
    const int bid = blockIdx.x;
    const int dt = bid & 1;
    const int st = (bid >> 1) & 31;
    const int kh = (bid >> 6) & 3;
    const int b  = bid >> 8;
    const int tid = threadIdx.x;
#pragma unroll
    for (int pp = 0; pp < 2; pp++) {
        int r  = pp * 32 + (tid >> 3);
        int c8 = (tid & 7) * 8;
        const u16* src = qkv + (size_t)(b * SEQ + st * 64 + r) * 3072 + 2560 + kh * 128 + dt * 64 + c8;
        uint4 v = *(const uint4*)src;
        tile[r][c8+0] = (u16)(v.x & 0xFFFF); tile[r][c8+1] = (u16)(v.x >> 16);
        tile[r][c8+2] = (u16)(v.y & 0xFFFF); tile[r][c8+3] = (u16)(v.y >> 16);
        tile[r][c8+4] = (u16)(v.z & 0xFFFF); tile[r][c8+5] = (u16)(v.z >> 16);
        tile[r][c8+6] = (u16)(v.w & 0xFFFF); tile[r][c8+7] = (u16)(v.w >> 16);
    }
    __syncthreads();
#pragma unroll
    for (int pp = 0; pp < 2; pp++) {
        int dr = pp * 32 + (tid >> 3);
        int s8 = (tid & 7) * 8;
        uint4 o;
        o.x = (u32)tile[s8+0][dr] | ((u32)tile[s8+1][dr] << 16);
        o.y = (u32)tile[s8+2][dr] | ((u32)tile[s8+3][dr] << 16);
        o.z = (u32)tile[s8+4][dr] | ((u32)tile[s8+5][dr] << 16);
        o.w = (u32)tile[s8+6][dr] | ((u32)tile[s8+7][dr] << 16);
        u16* dst = vt + ((size_t)((b * 4 + kh) * 128 + dt * 64 + dr)) * SEQ + st * 64 + s8;
        *(uint4*)dst = o;
    }
}

// ---------------- causal GQA flash attention: 128 q-rows/block, S^T softmax ----------------
// grid = 512: blocks 0..255 heavy q-tiles (qt=8+(c&7)), 256..511 the complements (qt=7-(c&7)).
// Each wave owns 32 q-rows (2 MFMA row-groups). S computed TRANSPOSED (A=K, B=Q) so the
// key-reduction is in-lane + 2 shuffle stages; P written as packed b64. K/V double-buffered
// via global_load_lds + raw s_barrier + manual vmcnt.
__global__ __launch_bounds__(256, 2) void flash_attn(const u16* __restrict__ qkv,
                                                     const u16* __restrict__ vt,
                                                     u16* __restrict__ ob) {
    __shared__ u16 lK[2][64 * 128];
    __shared__ u16 lV[2][128 * 64];
    __shared__ u16 lP[4][32 * 64];
    const int bidx = blockIdx.x;
    int bh, qt;
    if (bidx < 256) { bh = bidx >> 3;         qt = 8 + (bidx & 7); }
    else            { bh = (bidx - 256) >> 3; qt = 7 - ((bidx - 256) & 7); }
    const int b = bh >> 4, h = bh & 15, kh = h >> 2;
    const int tid = threadIdx.x;
    const int w = tid >> 6, lane = tid & 63;
    const int lr = lane & 15, quad = lane >> 4;

    // Q fragments (B-operand layout; scale*log2e pre-folded by rope_qk)
    bf16x8 qf[2][4];
#pragma unroll
    for (int qi = 0; qi < 2; qi++) {
        const u16* qbase = qkv + (size_t)(b * SEQ + qt * 128 + w * 32 + qi * 16 + lr) * 3072 + h * 128;
#pragma unroll
        for (int kk = 0; kk < 4; kk++)
            qf[qi][kk] = *(const bf16x8*)(qbase + kk * 32 + quad * 8);
    }

    const int krow = tid >> 4;                 // 0..15
    const int kchunk = (tid & 15) ^ krow;
    const int vrow = tid >> 3;                 // 0..31
    const int vchunk = (tid & 7) ^ (vrow & 7);
    const u16* kRow = qkv + (size_t)b * SEQ * 3072 + 2048 + kh * 128
                    + (size_t)krow * 3072 + kchunk * 8;
    const u16* vRow = vt + (size_t)(b * 4 + kh) * 128 * SEQ
                    + (size_t)vrow * SEQ + vchunk * 8;

    f32x4 o[2][8] = {};
    float m_st[2] = {-1e30f, -1e30f};
    float l_st[2] = {0.f, 0.f};

    const int nkt = 2 * qt + 2;
    // prologue: stage tile 0 into buffer 0
    {
        u16* lKd = &lK[0][0] + tid * 8;
        u16* lVd = &lV[0][0] + tid * 8;
#pragma unroll
        for (int i = 0; i < 4; i++) async16(kRow + (size_t)(i * 16) * 3072, lKd + i * 2048);
#pragma unroll
        for (int i = 0; i < 4; i++) async16(vRow + (size_t)(i * 32) * SEQ, lVd + i * 2048);
    }
    const int qg = qt * 128 + w * 32 + lr;

    int nb = 0;
    for (int kt = 0; kt < nkt; kt++) {
        if (kt + 1 < nkt) {
            u16* lKd = &lK[nb ^ 1][0] + tid * 8;
            u16* lVd = &lV[nb ^ 1][0] + tid * 8;
#pragma unroll
            for (int i = 0; i < 4; i++)
                async16(kRow + (size_t)((kt + 1) * 64 + i * 16) * 3072, lKd + i * 2048);
#pragma unroll
            for (int i = 0; i < 4; i++)
                async16(vRow + (size_t)(i * 32) * SEQ + (kt + 1) * 64, lVd + i * 2048);
            asm volatile("s_waitcnt vmcnt(8)" ::: "memory");
        } else {
            asm volatile("s_waitcnt vmcnt(0)" ::: "memory");
        }
        asm volatile("s_barrier" ::: "memory");   // all waves' cur-buffer staging complete

        const u16* lKc = &lK[nb][0];
        const u16* lVc = &lV[nb][0];

        // S^T = K Q^T : C cols = q (lane&15), rows = key (quad*4+r)
        f32x4 sc[2][4] = {};
#pragma unroll
        for (int nf = 0; nf < 4; nf++) {
#pragma unroll
            for (int kk = 0; kk < 4; kk++) {
                bf16x8 ak = *(const bf16x8*)&lKc[(nf * 16 + lr) * 128 + (((kk * 4 + quad) ^ lr) * 8)];
                sc[0][nf] = __builtin_amdgcn_mfma_f32_16x16x32_bf16(ak, qf[0][kk], sc[0][nf], 0, 0, 0);
                sc[1][nf] = __builtin_amdgcn_mfma_f32_16x16x32_bf16(ak, qf[1][kk], sc[1][nf], 0, 0, 0);
            }
        }

        const bool diag = (kt >= 2 * qt);
        const int kb = kt * 64 + quad * 4;
#pragma unroll
        for (int qi = 0; qi < 2; qi++) {
            float ps[4][4];
            float mnew = m_st[qi];
            const int qrow_g = qg + qi * 16;
#pragma unroll
            for (int nf = 0; nf < 4; nf++)
#pragma unroll
                for (int r = 0; r < 4; r++) {
                    float v = sc[qi][nf][r];
                    if (diag && (kb + nf * 16 + r) > qrow_g) v = -1e30f;
                    ps[nf][r] = v;
                    mnew = fmaxf(mnew, v);
                }
            mnew = fmaxf(mnew, __shfl_xor(mnew, 16));
            mnew = fmaxf(mnew, __shfl_xor(mnew, 32));
            float rsum = 0.f;
#pragma unroll
            for (int nf = 0; nf < 4; nf++)
#pragma unroll
                for (int r = 0; r < 4; r++) {
                    float e = exp2f(ps[nf][r] - mnew);
                    ps[nf][r] = e;
                    rsum += e;
                }
            rsum += __shfl_xor(rsum, 16);
            rsum += __shfl_xor(rsum, 32);
            float alpha = exp2f(m_st[qi] - mnew);
            l_st[qi] = l_st[qi] * alpha + rsum;
            m_st[qi] = mnew;
            // rescale o (o rows = quad*4+r; alpha lives at lane lr=q -> broadcast)
#pragma unroll
            for (int r = 0; r < 4; r++) {
                float ar = __shfl(alpha, quad * 4 + r, 16);
#pragma unroll
                for (int nd = 0; nd < 8; nd++) o[qi][nd][r] *= ar;
            }
            // write P: row = qi*16+lr, 4-key chunks c = nf*4+quad, swizzled by ^lr
            const int qrow = qi * 16 + lr;
#pragma unroll
            for (int nf = 0; nf < 4; nf++) {
                u32 lo = (u32)f2bf(ps[nf][0]) | ((u32)f2bf(ps[nf][1]) << 16);
                u32 hi = (u32)f2bf(ps[nf][2]) | ((u32)f2bf(ps[nf][3]) << 16);
                int c = (nf * 4 + quad) ^ lr;
                *(uint2*)&lP[w][qrow * 64 + c * 4] = make_uint2(lo, hi);
            }
        }

        // O += P V   (per-wave lP region; same-wave DS ordering, no barrier)
#pragma unroll
        for (int kf = 0; kf < 2; kf++) {
            bf16x8 pa[2];
#pragma unroll
            for (int qi = 0; qi < 2; qi++) {
                int c0 = (kf * 8 + quad * 2) ^ lr;
                int c1 = (kf * 8 + quad * 2 + 1) ^ lr;
                bf16x4 p0 = *(const bf16x4*)&lP[w][(qi * 16 + lr) * 64 + c0 * 4];
                bf16x4 p1 = *(const bf16x4*)&lP[w][(qi * 16 + lr) * 64 + c1 * 4];
                pa[qi] = __builtin_shufflevector(p0, p1, 0, 1, 2, 3, 4, 5, 6, 7);
            }
#pragma unroll
            for (int nd = 0; nd < 8; nd++) {
                bf16x8 vb = *(const bf16x8*)&lVc[(nd * 16 + lr) * 64 + (((kf * 4 + quad) ^ (lr & 7)) * 8)];
                o[0][nd] = __builtin_amdgcn_mfma_f32_16x16x32_bf16(pa[0], vb, o[0][nd], 0, 0, 0);
                o[1][nd] = __builtin_amdgcn_mfma_f32_16x16x32_bf16(pa[1], vb, o[1][nd], 0, 0, 0);
            }
        }

        asm volatile("s_barrier" ::: "memory");   // cur-buffer reads done -> next prefetch may overwrite
        nb ^= 1;
    }

    // epilogue
#pragma unroll
    for (int qi = 0; qi < 2; qi++) {
        float rinv = 1.0f / l_st[qi];
        u16* obase = ob + (size_t)(b * SEQ + qt * 128 + w * 32 + qi * 16) * 2048 + h * 128;
#pragma unroll
        for (int r = 0; r < 4; r++) {
            float rv = __shfl(rinv, quad * 4 + r, 16);
#pragma unroll
            for (int nd = 0; nd < 8; nd++)
                obase[(quad * 4 + r) * 2048 + nd * 16 + lr] = f2bf(o[qi][nd][r] * rv);
        }
    }
}

extern "C" void kernel_launch(void* const* d_in, const int* in_sizes, int n_in,
                              void* d_out, int out_size, void* d_ws, size_t ws_size,
                              hipStream_t stream) {
    (void)in_sizes; (void)n_in; (void)out_size; (void)ws_size;
    const float* x    = (const float*)d_in[0];
    const float* cosp = (const float*)d_in[1];
    const float* sinp = (const float*)d_in[2];
    const float* wq   = (const float*)d_in[3];
    const float* wk   = (const float*)d_in[4];
    const float* wv   = (const float*)d_in[5];
    const float* wo   = (const float*)d_in[6];
    float* out = (float*)d_out;

    char* ws = (char*)d_ws;
    u16* xb    = (u16*)(ws);                               // 16 MB (reused as ob)
    u16* qkvb  = (u16*)(ws + (size_t)16 * 1024 * 1024);    // 24 MB
    u16* wqkvT = (u16*)(ws + (size_t)40 * 1024 * 1024);    // 12 MB
    u16* woT   = (u16*)(ws + (size_t)52 * 1024 * 1024);    //  8 MB
    u16* vtb   = (u16*)(ws + (size_t)60 * 1024 * 1024);    //  4 MB
    u16* ob    = xb;                                       // alias: xb dead after QKV GEMM

    convert_bf16<<<8192, 256, 0, stream>>>(x, xb);
    tconv<<<dim3(32, 32), 256, 0, stream>>>(wq, wqkvT, 2048, 2048);
    tconv<<<dim3( 8, 32), 256, 0, stream>>>(wk, wqkvT + (size_t)2048 * 2048, 512, 2048);
    tconv<<<dim3( 8, 32), 256, 0, stream>>>(wv, wqkvT + (size_t)2560 * 2048, 512, 2048);
    tconv<<<dim3(32, 32), 256, 0, stream>>>(wo, woT, 2048, 2048);
    gemm128<false><<<dim3(24, 32), 256, 0, stream>>>(xb, wqkvT, (void*)qkvb, 4096, 3072, 2048);
    rope_qk<<<4096, 256, 0, stream>>>(qkvb, cosp, sinp);
    transpose_v<<<512, 256, 0, stream>>>(qkvb, vtb);
    flash_attn<<<512, 256, 0, stream>>>(qkvb, vtb, ob);
    gemm128<true><<<dim3(16, 32), 256, 0, stream>>>(ob, woT, (void*)out, 4096, 2048, 2048);
}

// Round 4
// 339.517 us; speedup vs baseline: 1.2780x; 1.0356x over previous
//
#include <hip/hip_runtime.h>
#include <stdint.h>

#define SEQ 2048
// B=2, DIM=2048, NH=16, NKV=4, HD=128, qkv width = 2048+512+512 = 3072

typedef uint16_t u16;
typedef uint32_t u32;
typedef __attribute__((ext_vector_type(4))) float f32x4;
typedef __attribute__((ext_vector_type(8))) __bf16 bf16x8;
typedef __attribute__((ext_vector_type(4))) __bf16 bf16x4;

__device__ __forceinline__ u16 f2bf(float f) {
    u32 u = __float_as_uint(f);
    u += 0x7FFFu + ((u >> 16) & 1u);   // RNE
    return (u16)(u >> 16);
}
__device__ __forceinline__ float bf2f(u16 h) {
    return __uint_as_float(((u32)h) << 16);
}
__device__ __forceinline__ void async16(const void* g, void* l) {
    auto gp = (__attribute__((address_space(1))) void*)const_cast<void*>(g);
    auto lp = (__attribute__((address_space(3))) void*)l;
    __builtin_amdgcn_global_load_lds(gp, lp, 16, 0, 0);
}

// ---------------- fp32 -> bf16 elementwise (x) ----------------
__global__ __launch_bounds__(256) void convert_bf16(const float* __restrict__ src,
                                                    u16* __restrict__ dst) {
    int i = blockIdx.x * 256 + threadIdx.x;      // one float4 per thread
    float4 v = ((const float4*)src)[i];
    u32 lo = (u32)f2bf(v.x) | ((u32)f2bf(v.y) << 16);
    u32 hi = (u32)f2bf(v.z) | ((u32)f2bf(v.w) << 16);
    ((uint2*)dst)[i] = make_uint2(lo, hi);
}

// ------------- fp32 [K][N] -> bf16 transposed [N][K] (weights) -------------
__global__ __launch_bounds__(256) void tconv(const float* __restrict__ src,
                                             u16* __restrict__ dst, int N, int K) {
    __shared__ float tile[64][65];
    const int n0 = blockIdx.x * 64, k0 = blockIdx.y * 64;
    const int tid = threadIdx.x;
#pragma unroll
    for (int p = 0; p < 4; p++) {
        int r = p * 16 + (tid >> 4);
        int c = (tid & 15) * 4;
        float4 v = *(const float4*)&src[(size_t)(k0 + r) * N + n0 + c];
        tile[r][c] = v.x; tile[r][c+1] = v.y; tile[r][c+2] = v.z; tile[r][c+3] = v.w;
    }
    __syncthreads();
#pragma unroll
    for (int p = 0; p < 4; p++) {
        int n = p * 16 + (tid >> 4);
        int kq = (tid & 15) * 4;
        u32 lo = (u32)f2bf(tile[kq+0][n]) | ((u32)f2bf(tile[kq+1][n]) << 16);
        u32 hi = (u32)f2bf(tile[kq+2][n]) | ((u32)f2bf(tile[kq+3][n]) << 16);
        *(uint2*)&dst[(size_t)(n0 + n) * K + k0 + kq] = make_uint2(lo, hi);
    }
}

// ---------------- bf16 GEMM: C[M,N] = A[M,K] * Bt[N,K]^T ----------------
template <bool F32OUT>
__global__ __launch_bounds__(256) void gemm128(const u16* __restrict__ A,
                                               const u16* __restrict__ Bt,
                                               void* __restrict__ Cv,
                                               int M, int N, int K) {
    __shared__ u16 lA[128 * 32];
    __shared__ u16 lB[128 * 32];
    const int tid = threadIdx.x;
    const int m0 = blockIdx.y * 128, n0 = blockIdx.x * 128;
    const int lane = tid & 63;
    const int lr = lane & 15, quad = lane >> 4;
    const int w = tid >> 6;
    const int wm = (w >> 1) * 64, wn = (w & 1) * 64;

    f32x4 acc[4][4] = {};

    const int srow = tid >> 2;
    const int schunk = (tid & 3) ^ (srow & 3);
    const u16* aS0 = A  + (size_t)(m0 + srow) * K + schunk * 8;
    const u16* aS1 = aS0 + (size_t)64 * K;
    const u16* bS0 = Bt + (size_t)(n0 + srow) * K + schunk * 8;
    const u16* bS1 = bS0 + (size_t)64 * K;
    u16* lAd = lA + tid * 8;
    u16* lBd = lB + tid * 8;

    for (int k0 = 0; k0 < K; k0 += 32) {
        __syncthreads();
        async16(aS0 + k0, lAd);
        async16(aS1 + k0, lAd + 2048);
        async16(bS0 + k0, lBd);
        async16(bS1 + k0, lBd + 2048);
        __syncthreads();
        bf16x8 af[4], bfr[4];
        const int cs = (quad ^ (lr & 3)) * 8;
#pragma unroll
        for (int i = 0; i < 4; i++)
            af[i] = *(const bf16x8*)&lA[(wm + i * 16 + lr) * 32 + cs];
#pragma unroll
        for (int i = 0; i < 4; i++)
            bfr[i] = *(const bf16x8*)&lB[(wn + i * 16 + lr) * 32 + cs];
#pragma unroll
        for (int mf = 0; mf < 4; mf++)
#pragma unroll
            for (int nf = 0; nf < 4; nf++)
                acc[mf][nf] = __builtin_amdgcn_mfma_f32_16x16x32_bf16(
                    af[mf], bfr[nf], acc[mf][nf], 0, 0, 0);
    }

#pragma unroll
    for (int mf = 0; mf < 4; mf++) {
#pragma unroll
        for (int nf = 0; nf < 4; nf++) {
#pragma unroll
            for (int r = 0; r < 4; r++) {
                size_t row = (size_t)(m0 + wm + mf * 16 + quad * 4 + r);
                size_t col = (size_t)(n0 + wn + nf * 16 + lr);
                if (F32OUT)
                    ((float*)Cv)[row * (size_t)N + col] = acc[mf][nf][r];
                else
                    ((u16*)Cv)[row * (size_t)N + col] = f2bf(acc[mf][nf][r]);
            }
        }
    }
}

// ---------------- RoPE on K only (Q rope is fused into flash_attn) ----------------
__global__ __launch_bounds__(256) void rope_k(u16* __restrict__ qkv,
                                              const float* __restrict__ cosp,
                                              const float* __restrict__ sinp) {
    const int t = blockIdx.x;
    const int spos = t & (SEQ - 1);
    const int tid = threadIdx.x;                  // one (r,i) pair per thread: 256 pairs = 512 cols
    u16* row = qkv + (size_t)t * 3072;
    const int col = 2048 + 2 * tid;
    const int ci = tid & 63;
    u32 v = *(u32*)(row + col);
    float tr = bf2f((u16)(v & 0xFFFFu));
    float ti = bf2f((u16)(v >> 16));
    float cs = cosp[spos * 64 + ci];
    float sn = sinp[spos * 64 + ci];
    float orr = tr * cs - ti * sn;
    float oi  = tr * sn + ti * cs;
    *(u32*)(row + col) = (u32)f2bf(orr) | ((u32)f2bf(oi) << 16);
}

// ---------------- V: qkv[t][2560 + kh*128 + d] -> vt[(b*4+kh)*128 + d][s] ----------------
__global__ __launch_bounds__(256) void transpose_v(const u16* __restrict__ qkv,
                                                   u16* __restrict__ vt) {
    __shared__ u16 tile[64][65];
    const int bid = blockIdx.x;
    const int dt = bid & 1;
    const int st = (bid >> 1) & 31;
    const int kh = (bid >> 6) & 3;
    const int b  = bid >> 8;
    const int tid = threadIdx.x;
#pragma unroll
    for (int pp = 0; pp < 2; pp++) {
        int r  = pp * 32 + (tid >> 3);
        int c8 = (tid & 7) * 8;
        const u16* src = qkv + (size_t)(b * SEQ + st * 64 + r) * 3072 + 2560 + kh * 128 + dt * 64 + c8;
        uint4 v = *(const uint4*)src;
        tile[r][c8+0] = (u16)(v.x & 0xFFFF); tile[r][c8+1] = (u16)(v.x >> 16);
        tile[r][c8+2] = (u16)(v.y & 0xFFFF); tile[r][c8+3] = (u16)(v.y >> 16);
        tile[r][c8+4] = (u16)(v.z & 0xFFFF); tile[r][c8+5] = (u16)(v.z >> 16);
        tile[r][c8+6] = (u16)(v.w & 0xFFFF); tile[r][c8+7] = (u16)(v.w >> 16);
    }
    __syncthreads();
#pragma unroll
    for (int pp = 0; pp < 2; pp++) {
        int dr = pp * 32 + (tid >> 3);
        int s8 = (tid & 7) * 8;
        uint4 o;
        o.x = (u32)tile[s8+0][dr] | ((u32)tile[s8+1][dr] << 16);
        o.y = (u32)tile[s8+2][dr] | ((u32)tile[s8+3][dr] << 16);
        o.z = (u32)tile[s8+4][dr] | ((u32)tile[s8+5][dr] << 16);
        o.w = (u32)tile[s8+6][dr] | ((u32)tile[s8+7][dr] << 16);
        u16* dst = vt + ((size_t)((b * 4 + kh) * 128 + dt * 64 + dr)) * SEQ + st * 64 + s8;
        *(uint4*)dst = o;
    }
}

// ---------------- causal GQA flash attention: uniform-duration K-split blocks ----------------
// grid = 256, 512 threads = 2 groups x 4 waves. Block (bh, a) processes q-tiles
// qt=8+a (heavy) then qt=7-a (light); for each tile the two groups split the kt range
// exactly in half -> every group does exactly (9+a)+(8-a)=17 iterations. Partial
// (m,l,O) merged in-block through LDS (f32). Q-RoPE+scale fused into Q-frag load.
__global__ __launch_bounds__(512, 2) void flash_attn(const u16* __restrict__ qkv,
                                                     const u16* __restrict__ vt,
                                                     const float* __restrict__ cosp,
                                                     const float* __restrict__ sinp,
                                                     u16* __restrict__ ob) {
    __shared__ u16 sh[49152];                    // 96 KB: [0,16384) g0 K|V, [16384,32768) g1 K|V, [32768,49152) P
    const int bidx = blockIdx.x;
    const int a  = bidx & 7;
    const int bh = bidx >> 3;
    const int b = bh >> 4, h = bh & 15, kh = h >> 2;
    const int tid = threadIdx.x;
    const int w = tid >> 6, lane = tid & 63;
    const int grp = w >> 2, wl = w & 3;
    const int lr = lane & 15, quad = lane >> 4;
    const float qscale = 0.088388347762f * 1.4426950408889634f;   // (1/sqrt(128))*log2(e)

    u16* lKg = sh + grp * 16384;                 // 64 rows x 128
    u16* lVg = lKg + 8192;                       // 128 rows x 64
    u16* lPw = sh + 32768 + w * 2048;            // 32 rows x 64 per wave

    const int tidg = tid & 255;
    const int krow = tidg >> 4;
    const int kchunk = (tidg & 15) ^ krow;
    const int vrow = tidg >> 3;
    const int vchunk = (tidg & 7) ^ (vrow & 7);
    const u16* kRow = qkv + (size_t)b * SEQ * 3072 + 2048 + kh * 128
                    + (size_t)krow * 3072 + kchunk * 8;
    const u16* vRow = vt + (size_t)(b * 4 + kh) * 128 * SEQ
                    + (size_t)vrow * SEQ + vchunk * 8;
    u16* lKd = lKg + tidg * 8;
    u16* lVd = lVg + tidg * 8;

    float* mO = (float*)sh;                      // merge: 128x128 f32 (over K/V regions, dead then)
    float* mM = (float*)(sh + 32768);            // merge: 128x(m,l) f32 (over P region, dead then)

    for (int p = 0; p < 2; p++) {
        const int qt = p ? (7 - a) : (8 + a);
        const int niters = p ? (8 - a) : (9 + a);
        const int kt0 = grp * niters;

        // Q fragments (A-layout) with fused RoPE + scale*log2e
        bf16x8 qf[2][4];
#pragma unroll
        for (int qi = 0; qi < 2; qi++) {
            const int token = qt * 128 + wl * 32 + qi * 16 + lr;
            const u16* qb = qkv + (size_t)(b * SEQ + token) * 3072 + h * 128;
#pragma unroll
            for (int kk = 0; kk < 4; kk++) {
                uint4 raw = *(const uint4*)(qb + kk * 32 + quad * 8);
                u32 rw[4] = {raw.x, raw.y, raw.z, raw.w};
                union { u16 us[8]; bf16x8 v; } fr;
#pragma unroll
                for (int pp = 0; pp < 4; pp++) {
                    int ci = kk * 16 + quad * 4 + pp;
                    float cv = cosp[token * 64 + ci];
                    float sv = sinp[token * 64 + ci];
                    float tr = bf2f((u16)(rw[pp] & 0xFFFFu));
                    float ti = bf2f((u16)(rw[pp] >> 16));
                    fr.us[2 * pp]     = f2bf((tr * cv - ti * sv) * qscale);
                    fr.us[2 * pp + 1] = f2bf((tr * sv + ti * cv) * qscale);
                }
                qf[qi][kk] = fr.v;
            }
        }

        f32x4 o[2][8] = {};
        float m_st[2] = {-1e30f, -1e30f};
        float l_st[2] = {0.f, 0.f};
        const int qg = qt * 128 + wl * 32 + lr;

        for (int t = 0; t < niters; t++) {
            const int kt = kt0 + t;
            // stage this group's K/V tile (single-buffered)
#pragma unroll
            for (int i = 0; i < 4; i++)
                async16(kRow + (size_t)(kt * 64 + i * 16) * 3072, lKd + i * 2048);
#pragma unroll
            for (int i = 0; i < 4; i++)
                async16(vRow + (size_t)(i * 32) * SEQ + kt * 64, lVd + i * 2048);
            asm volatile("s_waitcnt vmcnt(0)" ::: "memory");
            asm volatile("s_barrier" ::: "memory");

            // S^T = K Q^T : C cols = q (lane&15), rows = key (quad*4+r)
            f32x4 sc[2][4] = {};
#pragma unroll
            for (int nf = 0; nf < 4; nf++) {
#pragma unroll
                for (int kk = 0; kk < 4; kk++) {
                    bf16x8 ak = *(const bf16x8*)&lKg[(nf * 16 + lr) * 128 + (((kk * 4 + quad) ^ lr) * 8)];
                    sc[0][nf] = __builtin_amdgcn_mfma_f32_16x16x32_bf16(ak, qf[0][kk], sc[0][nf], 0, 0, 0);
                    sc[1][nf] = __builtin_amdgcn_mfma_f32_16x16x32_bf16(ak, qf[1][kk], sc[1][nf], 0, 0, 0);
                }
            }

            const int kb = kt * 64 + quad * 4;
#pragma unroll
            for (int qi = 0; qi < 2; qi++) {
                float ps[4][4];
                float mnew = m_st[qi];
                const int qrow_g = qg + qi * 16;
#pragma unroll
                for (int nf = 0; nf < 4; nf++)
#pragma unroll
                    for (int r = 0; r < 4; r++) {
                        float v = sc[qi][nf][r];
                        if ((kb + nf * 16 + r) > qrow_g) v = -1e30f;
                        ps[nf][r] = v;
                        mnew = fmaxf(mnew, v);
                    }
                mnew = fmaxf(mnew, __shfl_xor(mnew, 16));
                mnew = fmaxf(mnew, __shfl_xor(mnew, 32));
                float rsum = 0.f;
#pragma unroll
                for (int nf = 0; nf < 4; nf++)
#pragma unroll
                    for (int r = 0; r < 4; r++) {
                        float e = exp2f(ps[nf][r] - mnew);
                        ps[nf][r] = e;
                        rsum += e;
                    }
                rsum += __shfl_xor(rsum, 16);
                rsum += __shfl_xor(rsum, 32);
                float alpha = exp2f(m_st[qi] - mnew);
                l_st[qi] = l_st[qi] * alpha + rsum;
                m_st[qi] = mnew;
#pragma unroll
                for (int r = 0; r < 4; r++) {
                    float ar = __shfl(alpha, quad * 4 + r, 16);
#pragma unroll
                    for (int nd = 0; nd < 8; nd++) o[qi][nd][r] *= ar;
                }
                const int qrow = qi * 16 + lr;
#pragma unroll
                for (int nf = 0; nf < 4; nf++) {
                    u32 lo = (u32)f2bf(ps[nf][0]) | ((u32)f2bf(ps[nf][1]) << 16);
                    u32 hi = (u32)f2bf(ps[nf][2]) | ((u32)f2bf(ps[nf][3]) << 16);
                    int c = (nf * 4 + quad) ^ lr;
                    *(uint2*)&lPw[qrow * 64 + c * 4] = make_uint2(lo, hi);
                }
            }

            // O += P V (per-wave lP region; same-wave DS ordering)
#pragma unroll
            for (int kf = 0; kf < 2; kf++) {
                bf16x8 pa[2];
#pragma unroll
                for (int qi = 0; qi < 2; qi++) {
                    int c0 = (kf * 8 + quad * 2) ^ lr;
                    int c1 = (kf * 8 + quad * 2 + 1) ^ lr;
                    bf16x4 p0 = *(const bf16x4*)&lPw[(qi * 16 + lr) * 64 + c0 * 4];
                    bf16x4 p1 = *(const bf16x4*)&lPw[(qi * 16 + lr) * 64 + c1 * 4];
                    pa[qi] = __builtin_shufflevector(p0, p1, 0, 1, 2, 3, 4, 5, 6, 7);
                }
#pragma unroll
                for (int nd = 0; nd < 8; nd++) {
                    bf16x8 vb = *(const bf16x8*)&lVg[(nd * 16 + lr) * 64 + (((kf * 4 + quad) ^ (lr & 7)) * 8)];
                    o[0][nd] = __builtin_amdgcn_mfma_f32_16x16x32_bf16(pa[0], vb, o[0][nd], 0, 0, 0);
                    o[1][nd] = __builtin_amdgcn_mfma_f32_16x16x32_bf16(pa[1], vb, o[1][nd], 0, 0, 0);
                }
            }

            asm volatile("s_barrier" ::: "memory");   // reads done -> next iter may restage
        }

        // ---- in-block merge of the two K-halves ----
        __syncthreads();
        if (grp == 1) {
#pragma unroll
            for (int qi = 0; qi < 2; qi++) {
#pragma unroll
                for (int r = 0; r < 4; r++) {
                    int row = wl * 32 + qi * 16 + quad * 4 + r;
#pragma unroll
                    for (int nd = 0; nd < 8; nd++)
                        mO[row * 128 + nd * 16 + lr] = o[qi][nd][r];
                }
                if (quad == 0) {
                    int rowl = wl * 32 + qi * 16 + lr;
                    mM[rowl * 2]     = m_st[qi];
                    mM[rowl * 2 + 1] = l_st[qi];
                }
            }
        }
        __syncthreads();
        if (grp == 0) {
#pragma unroll
            for (int qi = 0; qi < 2; qi++) {
                int rowl = wl * 32 + qi * 16 + lr;
                float m1 = mM[rowl * 2], l1 = mM[rowl * 2 + 1];
                float M  = fmaxf(m_st[qi], m1);
                float a0 = exp2f(m_st[qi] - M);
                float a1 = exp2f(m1 - M);
                float li = 1.0f / (l_st[qi] * a0 + l1 * a1);
                u16* obase = ob + (size_t)(b * SEQ + qt * 128 + wl * 32 + qi * 16) * 2048 + h * 128;
#pragma unroll
                for (int r = 0; r < 4; r++) {
                    float a0b = __shfl(a0, quad * 4 + r, 16);
                    float a1b = __shfl(a1, quad * 4 + r, 16);
                    float lib = __shfl(li, quad * 4 + r, 16);
                    int row = wl * 32 + qi * 16 + quad * 4 + r;
#pragma unroll
                    for (int nd = 0; nd < 8; nd++) {
                        float val = (o[qi][nd][r] * a0b + mO[row * 128 + nd * 16 + lr] * a1b) * lib;
                        obase[(quad * 4 + r) * 2048 + nd * 16 + lr] = f2bf(val);
                    }
                }
            }
        }
        __syncthreads();   // merge reads done before next phase restages K/V regions
    }
}

extern "C" void kernel_launch(void* const* d_in, const int* in_sizes, int n_in,
                              void* d_out, int out_size, void* d_ws, size_t ws_size,
                              hipStream_t stream) {
    (void)in_sizes; (void)n_in; (void)out_size; (void)ws_size;
    const float* x    = (const float*)d_in[0];
    const float* cosp = (const float*)d_in[1];
    const float* sinp = (const float*)d_in[2];
    const float* wq   = (const float*)d_in[3];
    const float* wk   = (const float*)d_in[4];
    const float* wv   = (const float*)d_in[5];
    const float* wo   = (const float*)d_in[6];
    float* out = (float*)d_out;

    char* ws = (char*)d_ws;
    u16* xb    = (u16*)(ws);                               // 16 MB (reused as ob)
    u16* qkvb  = (u16*)(ws + (size_t)16 * 1024 * 1024);    // 24 MB
    u16* wqkvT = (u16*)(ws + (size_t)40 * 1024 * 1024);    // 12 MB
    u16* woT   = (u16*)(ws + (size_t)52 * 1024 * 1024);    //  8 MB
    u16* vtb   = (u16*)(ws + (size_t)60 * 1024 * 1024);    //  4 MB
    u16* ob    = xb;                                       // alias: xb dead after QKV GEMM

    convert_bf16<<<8192, 256, 0, stream>>>(x, xb);
    tconv<<<dim3(32, 32), 256, 0, stream>>>(wq, wqkvT, 2048, 2048);
    tconv<<<dim3( 8, 32), 256, 0, stream>>>(wk, wqkvT + (size_t)2048 * 2048, 512, 2048);
    tconv<<<dim3( 8, 32), 256, 0, stream>>>(wv, wqkvT + (size_t)2560 * 2048, 512, 2048);
    tconv<<<dim3(32, 32), 256, 0, stream>>>(wo, woT, 2048, 2048);
    gemm128<false><<<dim3(24, 32), 256, 0, stream>>>(xb, wqkvT, (void*)qkvb, 4096, 3072, 2048);
    rope_k<<<4096, 256, 0, stream>>>(qkvb, cosp, sinp);
    transpose_v<<<512, 256, 0, stream>>>(qkvb, vtb);
    flash_attn<<<256, 512, 0, stream>>>(qkvb, vtb, cosp, sinp, ob);
    gemm128<true><<<dim3(16, 32), 256, 0, stream>>>(ob, woT, (void*)out, 4096, 2048, 2048);
}